// Round 9
// baseline (35.359 us; speedup 1.0000x reference)
//
#include <hip/hip_runtime.h>
#include <math.h>

#define LC 8
#define FAC 120
#define KS 5
#define KK 25
#define IWID 64
#define NH 60
#define SS 3600
#define CHUNK 512
#define NBLK 128         // (plane 0..15) x (l 0..7); block owns one output row

using bf16x8 = __attribute__((ext_vector_type(8))) short;
using f32x4  = __attribute__((ext_vector_type(4))) float;

__device__ __forceinline__ short f2bf(float v) {
  unsigned u = __builtin_bit_cast(unsigned, v);
  unsigned r = u + 0x7FFFu + ((u >> 16) & 1u);   // RNE
  return (short)(r >> 16);
}
__device__ __forceinline__ float bf2f(short h) {
  unsigned u = ((unsigned)(unsigned short)h) << 16;
  return __builtin_bit_cast(float, u);
}

// One block = one output row (plane, l). Builds M-slice in LDS, chunks the
// 3600 pixels through MFMA, exps into LDS, normalizes, writes once.
// No workspace, no inter-block communication, idempotent across replays.
__global__ __launch_bounds__(1024) void fused(const float* __restrict__ x,
                                              const float* __restrict__ kern,
                                              float* __restrict__ out) {
  __shared__ short pat_hi[CHUNK][32];
  __shared__ short pat_lo[CHUNK][32];
  __shared__ short Mh[128][32];    // f-rows 120..127 zero, q 25..31 zero
  __shared__ short Ml[128][32];
  __shared__ float xsq_s[CHUNK];
  __shared__ float exprow[SS];
  __shared__ unsigned Kpk[32];     // packed (hi<<16)|lo bf16 split of K_l
  __shared__ float sred[17];       // [0..15] wave sums, [16] msq

  const int tid = threadIdx.x;
  const int bid = blockIdx.x;
  const int plane = bid >> 3;      // b*2 + cp
  const int l = bid & 7;
  const int w = tid >> 6;
  const int lane = tid & 63;
  const float* xp = x + plane * (IWID * IWID);
  const int rowbase = ((plane >> 1) * 16 + (plane & 1) * 8 + l) * SS;

  if (bid == 0 && tid < LC * KK) out[460800 + tid] = kern[tid];  // tuple tail

  // ---- stage packed K split + exact msq ----
  if (tid < 32) {
    unsigned pk = 0;
    if (tid < KK) {
      const float v = kern[l * KK + tid];
      const short hs = f2bf(v);
      const short ls = f2bf(v - bf2f(hs));
      pk = ((unsigned)(unsigned short)hs << 16) | (unsigned)(unsigned short)ls;
    }
    Kpk[tid] = pk;
  } else if (tid == 32) {
    const float* Kl = kern + l * KK;
    float s = 0.f;
    #pragma unroll
    for (int q = 0; q < KK; ++q) s = fmaf(Kl[q], Kl[q], s);
    sred[16] = s;
  }
  __syncthreads();

  // ---- build M rows (threads 0..127, one f each) ----
  if (tid < 128) {
    const int f = tid;
    bf16x8 H[4], L[4];
    #pragma unroll
    for (int c = 0; c < 4; ++c) { H[c] = (bf16x8)(short)0; L[c] = (bf16x8)(short)0; }
    if (f < FAC) {
      int avail[KS] = {0, 1, 2, 3, 4};
      int perm[KS];
      int rem = f;
      const int divs[4] = {24, 6, 2, 1};
      for (int i = 0; i < 4; ++i) {
        const int d = rem / divs[i];
        rem -= d * divs[i];
        perm[i] = avail[d];
        for (int j = d; j < 4 - i; ++j) avail[j] = avail[j + 1];
      }
      perm[4] = avail[0];
      #pragma unroll
      for (int a = 0; a < KS; ++a)
        #pragma unroll
        for (int d = 0; d < KS; ++d) {
          const int q = a * KS + d;
          const unsigned k = Kpk[perm[a] * KS + perm[d]];
          H[q >> 3][q & 7] = (short)(k >> 16);
          L[q >> 3][q & 7] = (short)(k & 0xFFFFu);
        }
    }
    #pragma unroll
    for (int c = 0; c < 4; ++c) {
      *(bf16x8*)&Mh[f][c * 8] = H[c];
      *(bf16x8*)&Ml[f][c * 8] = L[c];
    }
  }
  __syncthreads();

  // ---- A fragments (M) once, registers ----
  const short* ah = &Mh[0][0] + (lane & 15) * 32 + (lane >> 4) * 8;
  const short* al = &Ml[0][0] + (lane & 15) * 32 + (lane >> 4) * 8;
  bf16x8 Ah[8], Al[8];
  #pragma unroll
  for (int t = 0; t < 8; ++t) {
    Ah[t] = *(const bf16x8*)(ah + t * 512);
    Al[t] = *(const bf16x8*)(al + t * 512);
  }
  const float msq = sred[16];
  const f32x4 Z = {0.f, 0.f, 0.f, 0.f};
  float psum = 0.f;

  // ---- chunk loop over the row's 3600 pixels ----
  for (int s0 = 0; s0 < SS; s0 += CHUNK) {
    const int npix = min(CHUNK, SS - s0);
    if (tid < npix) {
      const int s = s0 + tid;
      const int ih = s / NH;
      const int iw = s - ih * NH;
      const float* xb = xp + ih * IWID + iw;
      float p[KK];
      #pragma unroll
      for (int a = 0; a < KS; ++a)
        #pragma unroll
        for (int d = 0; d < KS; ++d)
          p[a * KS + d] = xb[a * IWID + d];
      float xs = 0.f;
      #pragma unroll
      for (int q = 0; q < KK; ++q) xs = fmaf(p[q], p[q], xs);
      xsq_s[tid] = xs;
      bf16x8 ph[4], pl[4];
      #pragma unroll
      for (int c = 0; c < 4; ++c) { ph[c] = (bf16x8)(short)0; pl[c] = (bf16x8)(short)0; }
      #pragma unroll
      for (int q = 0; q < KK; ++q) {
        const short hs = f2bf(p[q]);
        ph[q >> 3][q & 7] = hs;
        pl[q >> 3][q & 7] = f2bf(p[q] - bf2f(hs));
      }
      #pragma unroll
      for (int c = 0; c < 4; ++c) {
        *(bf16x8*)&pat_hi[tid][c * 8] = ph[c];
        *(bf16x8*)&pat_lo[tid][c * 8] = pl[c];
      }
    }
    __syncthreads();
    #pragma unroll
    for (int jt = 0; jt < 2; ++jt) {
      const int j = w + jt * 16;          // 32 j-tiles over 16 waves
      if (j * 16 < npix) {
        const int prow = j * 16 + (lane & 15);
        const bf16x8 BH = *(const bf16x8*)&pat_hi[prow][(lane >> 4) * 8];
        const bf16x8 BL = *(const bf16x8*)&pat_lo[prow][(lane >> 4) * 8];
        const float xs = xsq_s[prow];
        float mx = -INFINITY;
        #pragma unroll
        for (int t = 0; t < 8; ++t) {
          f32x4 C = __builtin_amdgcn_mfma_f32_16x16x32_bf16(Ah[t], BH, Z, 0, 0, 0);
          C = __builtin_amdgcn_mfma_f32_16x16x32_bf16(Al[t], BH, C, 0, 0, 0);
          C = __builtin_amdgcn_mfma_f32_16x16x32_bf16(Ah[t], BL, C, 0, 0, 0);
          if (t < 7) {
            mx = fmaxf(mx, fmaxf(fmaxf(C[0], C[1]), fmaxf(C[2], C[3])));
          } else if (lane < 32) {   // f-rows 112..119 valid, 120..127 pad
            mx = fmaxf(mx, fmaxf(fmaxf(C[0], C[1]), fmaxf(C[2], C[3])));
          }
        }
        mx = fmaxf(mx, __shfl_xor(mx, 16));
        mx = fmaxf(mx, __shfl_xor(mx, 32));
        if (lane < 16) {
          // exp(-feature); feature = msq + xsq - 2*max >= 0 (min distance)
          const float e = expf(2.f * mx - msq - xs);
          exprow[s0 + j * 16 + lane] = e;
          psum += e;
        }
      }
    }
    __syncthreads();
  }

  // ---- block-reduce row sum, normalize, single coalesced write ----
  #pragma unroll
  for (int off = 32; off >= 1; off >>= 1) psum += __shfl_xor(psum, off);
  if (lane == 0) sred[w] = psum;
  __syncthreads();
  float tot = 0.f;
  #pragma unroll
  for (int i = 0; i < 16; ++i) tot += sred[i];
  const float inv = 1.0f / tot;
  #pragma unroll
  for (int i = 0; i < 4; ++i) {
    const int idx = tid + i * 1024;
    if (idx < SS) out[rowbase + idx] = exprow[idx] * inv;
  }
}

extern "C" void kernel_launch(void* const* d_in, const int* in_sizes, int n_in,
                              void* d_out, int out_size, void* d_ws, size_t ws_size,
                              hipStream_t stream) {
  const float* x = (const float*)d_in[0];
  const float* kern = (const float*)d_in[1];
  float* out = (float*)d_out;
  hipLaunchKernelGGL(fused, dim3(NBLK), dim3(1024), 0, stream, x, kern, out);
}

// Round 10
// 31.327 us; speedup vs baseline: 1.1287x; 1.1287x over previous
//
#include <hip/hip_runtime.h>
#include <math.h>

#define LC 8
#define FAC 120
#define KS 5
#define KK 25
#define IWID 64
#define NH 60
#define SS 3600
#define NBLK 128         // (plane 0..15) x (l 0..7); block owns one output row

using bf16x8 = __attribute__((ext_vector_type(8))) short;
using f32x4  = __attribute__((ext_vector_type(4))) float;

__device__ __forceinline__ short f2bf(float v) {
  unsigned u = __builtin_bit_cast(unsigned, v);
  unsigned r = u + 0x7FFFu + ((u >> 16) & 1u);   // RNE
  return (short)(r >> 16);
}
__device__ __forceinline__ float bf2f(short h) {
  unsigned u = ((unsigned)(unsigned short)h) << 16;
  return __builtin_bit_cast(float, u);
}

// One block = one output row (plane, l). x-plane resident in LDS; each wave
// builds its own B-fragments from the plane -> NO barriers in the main loop.
// Block-local softmax denominator -> single kernel, no ws, idempotent.
__global__ __launch_bounds__(1024) void fused(const float* __restrict__ x,
                                              const float* __restrict__ kern,
                                              float* __restrict__ out) {
  __shared__ float plane_s[IWID * IWID];   // 16 KB
  __shared__ short Mh[128][32];            // f-rows 120..127 zero, q 25..31 zero
  __shared__ short Ml[128][32];
  __shared__ float exprow[SS];             // 14.4 KB
  __shared__ float sred[17];               // [0..15] wave sums, [16] msq

  const int tid = threadIdx.x;
  const int bid = blockIdx.x;
  const int plane = bid >> 3;              // b*2 + cp
  const int l = bid & 7;
  const int w = tid >> 6;
  const int lane = tid & 63;
  const int rowbase = ((plane >> 1) * 16 + (plane & 1) * 8 + l) * SS;

  // x-plane -> LDS (1024 x float4 = 16 KB, coalesced)
  ((f32x4*)plane_s)[tid] = ((const f32x4*)(x + plane * (IWID * IWID)))[tid];

  // M-slice build: thread f (0..127) gathers permuted K_l from global (L2-hot)
  if (tid < 128) {
    const int f = tid;
    bf16x8 H[4], L[4];
    #pragma unroll
    for (int c = 0; c < 4; ++c) { H[c] = (bf16x8)(short)0; L[c] = (bf16x8)(short)0; }
    if (f < FAC) {
      int avail[KS] = {0, 1, 2, 3, 4};
      int perm[KS];
      int rem = f;
      const int divs[4] = {24, 6, 2, 1};
      for (int i = 0; i < 4; ++i) {
        const int d = rem / divs[i];
        rem -= d * divs[i];
        perm[i] = avail[d];
        for (int j = d; j < 4 - i; ++j) avail[j] = avail[j + 1];
      }
      perm[4] = avail[0];
      const float* Kl = kern + l * KK;
      #pragma unroll
      for (int a = 0; a < KS; ++a)
        #pragma unroll
        for (int d = 0; d < KS; ++d) {
          const int q = a * KS + d;
          const float v = Kl[perm[a] * KS + perm[d]];
          const short hs = f2bf(v);
          H[q >> 3][q & 7] = hs;
          L[q >> 3][q & 7] = f2bf(v - bf2f(hs));
        }
    }
    #pragma unroll
    for (int c = 0; c < 4; ++c) {
      *(bf16x8*)&Mh[f][c * 8] = H[c];
      *(bf16x8*)&Ml[f][c * 8] = L[c];
    }
  } else if (tid == 128) {
    const float* Kl = kern + l * KK;
    float s = 0.f;
    #pragma unroll
    for (int q = 0; q < KK; ++q) s = fmaf(Kl[q], Kl[q], s);
    sred[16] = s;
  }
  if (bid == 0 && tid >= 256 && tid < 256 + LC * KK)
    out[460800 + (tid - 256)] = kern[tid - 256];   // tuple tail
  __syncthreads();   // plane + M + msq ready (only barrier before main loop)

  // A fragments (M) once per wave, registers
  const short* ah = &Mh[0][0] + (lane & 15) * 32 + (lane >> 4) * 8;
  const short* al = &Ml[0][0] + (lane & 15) * 32 + (lane >> 4) * 8;
  bf16x8 Ah[8], Al[8];
  #pragma unroll
  for (int t = 0; t < 8; ++t) {
    Ah[t] = *(const bf16x8*)(ah + t * 512);
    Al[t] = *(const bf16x8*)(al + t * 512);
  }
  const float msq = sred[16];
  const f32x4 Z = {0.f, 0.f, 0.f, 0.f};
  const int h = lane >> 4;
  const int r = lane & 15;
  float psum = 0.f;

  // main loop: 225 j-tiles striped over 16 waves; barrier-free
  for (int j = w; j < 225; j += 16) {
    const int s = j * 16 + r;               // this lane's pixel (column of B)
    const int ih = s / NH;
    const int iw = s - ih * NH;
    const int base = ih * IWID + iw;
    // per-lane B elements q in [8h, 8h+8) from the LDS plane
    float p[8];
    float psq = 0.f;
    #pragma unroll
    for (int e = 0; e < 8; ++e) {
      const int q = (h << 3) + e;
      const int qc = q < KK ? q : KK - 1;
      const int a = (qc * 13) >> 6;         // qc/5
      const int d = qc - a * KS;
      float v = plane_s[base + a * IWID + d];
      v = (q < KK) ? v : 0.f;
      p[e] = v;
      psq = fmaf(v, v, psq);
    }
    psq += __shfl_xor(psq, 16);
    psq += __shfl_xor(psq, 32);             // full ||patch||^2 in all lanes
    bf16x8 BH, BL;
    #pragma unroll
    for (int e = 0; e < 8; ++e) {
      const short hs = f2bf(p[e]);
      BH[e] = hs;
      BL[e] = f2bf(p[e] - bf2f(hs));
    }
    float mx = -INFINITY;
    #pragma unroll
    for (int t = 0; t < 8; ++t) {
      f32x4 C = __builtin_amdgcn_mfma_f32_16x16x32_bf16(Ah[t], BH, Z, 0, 0, 0);
      C = __builtin_amdgcn_mfma_f32_16x16x32_bf16(Al[t], BH, C, 0, 0, 0);
      C = __builtin_amdgcn_mfma_f32_16x16x32_bf16(Ah[t], BL, C, 0, 0, 0);
      if (t < 7) {
        mx = fmaxf(mx, fmaxf(fmaxf(C[0], C[1]), fmaxf(C[2], C[3])));
      } else if (lane < 32) {   // tile 7: f-rows 112..119 valid, 120..127 pad
        mx = fmaxf(mx, fmaxf(fmaxf(C[0], C[1]), fmaxf(C[2], C[3])));
      }
    }
    mx = fmaxf(mx, __shfl_xor(mx, 16));
    mx = fmaxf(mx, __shfl_xor(mx, 32));
    if (lane < 16) {
      // exp(-feature); feature = msq + xsq - 2*max >= 0 (min distance)
      const float e = expf(2.f * mx - msq - psq);
      exprow[s] = e;
      psum += e;
    }
  }

  // block-reduce row sum, normalize, coalesced write
  #pragma unroll
  for (int off = 32; off >= 1; off >>= 1) psum += __shfl_xor(psum, off);
  if (lane == 0) sred[w] = psum;
  __syncthreads();
  float tot = 0.f;
  #pragma unroll
  for (int i = 0; i < 16; ++i) tot += sred[i];
  const float inv = 1.0f / tot;
  #pragma unroll
  for (int i = 0; i < 4; ++i) {
    const int idx = tid + i * 1024;
    if (idx < SS) out[rowbase + idx] = exprow[idx] * inv;
  }
}

extern "C" void kernel_launch(void* const* d_in, const int* in_sizes, int n_in,
                              void* d_out, int out_size, void* d_ws, size_t ws_size,
                              hipStream_t stream) {
  const float* x = (const float*)d_in[0];
  const float* kern = (const float*)d_in[1];
  float* out = (float*)d_out;
  hipLaunchKernelGGL(fused, dim3(NBLK), dim3(1024), 0, stream, x, kern, out);
}

// Round 12
// 25.648 us; speedup vs baseline: 1.3786x; 1.2214x over previous
//
#include <hip/hip_runtime.h>
#include <math.h>

#define LC 8
#define FAC 120
#define KS 5
#define KK 25
#define IWID 64
#define NH 60
#define SS 3600
#define HALF0PX 1792     // half0: tiles 0..111 (px 0..1791); half1: 113 tiles (px 1792..3599)
#define NBLK 256         // 128 rows (plane,l) x 2 halves

using bf16x8 = __attribute__((ext_vector_type(8))) short;
using f32x4  = __attribute__((ext_vector_type(4))) float;

__device__ __forceinline__ short f2bf(float v) {
  unsigned u = __builtin_bit_cast(unsigned, v);
  unsigned r = u + 0x7FFFu + ((u >> 16) & 1u);   // RNE (used only in M build)
  return (short)(r >> 16);
}
__device__ __forceinline__ float bf2f(short h) {
  unsigned u = ((unsigned)(unsigned short)h) << 16;
  return __builtin_bit_cast(float, u);
}

// One block = half of one output row (plane,l). Whole x-plane in LDS, per-wave
// B-build (truncation split), barrier-free main loop, block-local exp+partial
// sum, pairwise self-validating sum exchange through ws, coalesced write.
__global__ __launch_bounds__(1024) void fused(const float* __restrict__ x,
                                              const float* __restrict__ kern,
                                              unsigned* __restrict__ wsp,
                                              float* __restrict__ out) {
  __shared__ float plane_s[IWID * IWID];       // 16 KB
  __shared__ short Mh[128][32];                // f 120..127 zero, q 25..31 zero
  __shared__ short Ml[128][32];
  __shared__ float exprow[1808];               // this half's exp values
  __shared__ float sred[17];                   // [0..15] wave sums, [16] msq

  const int tid = threadIdx.x;
  const int bid = blockIdx.x;
  const int row = bid >> 1;                    // plane*8 + l
  const int half = bid & 1;
  const int plane = row >> 3;
  const int l = row & 7;
  const int w = tid >> 6;
  const int lane = tid & 63;
  const int h = lane >> 4;
  const int r = lane & 15;
  const int rowbase = ((plane >> 1) * 16 + (plane & 1) * 8 + l) * SS;
  const int px0 = half * HALF0PX;
  const int NT = 112 + half;                   // tiles this half

  // x-plane -> LDS (1024 x float4, coalesced)
  ((f32x4*)plane_s)[tid] = ((const f32x4*)(x + plane * (IWID * IWID)))[tid];
  if (bid == 0 && tid < LC * KK) out[460800 + tid] = kern[tid];   // tuple tail

  // M-slice build (threads 0..127, one f each; RNE split; once per block)
  if (tid < 128) {
    const int f = tid;
    bf16x8 H[4], L[4];
    #pragma unroll
    for (int c = 0; c < 4; ++c) { H[c] = (bf16x8)(short)0; L[c] = (bf16x8)(short)0; }
    if (f < FAC) {
      int avail[KS] = {0, 1, 2, 3, 4};
      int perm[KS];
      int rem = f;
      const int divs[4] = {24, 6, 2, 1};
      for (int i = 0; i < 4; ++i) {
        const int d = rem / divs[i];
        rem -= d * divs[i];
        perm[i] = avail[d];
        for (int j = d; j < 4 - i; ++j) avail[j] = avail[j + 1];
      }
      perm[4] = avail[0];
      const float* Kl = kern + l * KK;
      #pragma unroll
      for (int a = 0; a < KS; ++a)
        #pragma unroll
        for (int d = 0; d < KS; ++d) {
          const int q = a * KS + d;
          const float v = Kl[perm[a] * KS + perm[d]];
          const short hs = f2bf(v);
          H[q >> 3][q & 7] = hs;
          L[q >> 3][q & 7] = f2bf(v - bf2f(hs));
        }
    }
    #pragma unroll
    for (int c = 0; c < 4; ++c) {
      *(bf16x8*)&Mh[f][c * 8] = H[c];
      *(bf16x8*)&Ml[f][c * 8] = L[c];
    }
  } else if (tid == 128) {
    const float* Kl = kern + l * KK;
    float s = 0.f;
    #pragma unroll
    for (int q = 0; q < KK; ++q) s = fmaf(Kl[q], Kl[q], s);
    sred[16] = s;
  }
  __syncthreads();   // plane + M + msq ready

  // A fragments once per wave
  const short* ah = &Mh[0][0] + r * 32 + h * 8;
  const short* al = &Ml[0][0] + r * 32 + h * 8;
  bf16x8 Ah[8], Al[8];
  #pragma unroll
  for (int t = 0; t < 8; ++t) {
    Ah[t] = *(const bf16x8*)(ah + t * 512);
    Al[t] = *(const bf16x8*)(al + t * 512);
  }
  const float msq = sred[16];
  const f32x4 Z = {0.f, 0.f, 0.f, 0.f};

  // per-lane gather offsets + multiplicative mask for q = 8h..8h+7
  // (mask = 0 zeroes OOB/pad elements; offset 0 keeps the read in-bounds)
  int offs[8];
  float mk[8];
  #pragma unroll
  for (int e = 0; e < 8; ++e) {
    const int q = (h << 3) + e;
    const bool valid = (q < KK);
    offs[e] = valid ? ((q / KS) * IWID + (q % KS)) : 0;
    mk[e] = valid ? 1.f : 0.f;
  }

  float psum = 0.f;
  // main loop: NT 16-px tiles striped over 16 waves, barrier-free
  #pragma unroll 1
  for (int j = w; j < NT; j += 16) {
    const int px = px0 + (j << 4) + r;
    const int ih = px / NH;
    const int iw = px - ih * NH;
    const int base = ih * IWID + iw;
    bf16x8 BH, BL;
    float psq = 0.f;
    #pragma unroll
    for (int e = 0; e < 8; ++e) {
      const float v = plane_s[base + offs[e]] * mk[e];
      psq = fmaf(v, v, psq);
      const unsigned u = __builtin_bit_cast(unsigned, v);
      BH[e] = (short)(u >> 16);                                    // trunc hi
      const float hf = __builtin_bit_cast(float, u & 0xFFFF0000u);
      BL[e] = (short)(__builtin_bit_cast(unsigned, v - hf) >> 16); // trunc lo
    }
    psq += __shfl_xor(psq, 16);
    psq += __shfl_xor(psq, 32);
    float mx = -INFINITY;
    #pragma unroll
    for (int t = 0; t < 8; ++t) {
      f32x4 C = __builtin_amdgcn_mfma_f32_16x16x32_bf16(Ah[t], BH, Z, 0, 0, 0);
      C = __builtin_amdgcn_mfma_f32_16x16x32_bf16(Al[t], BH, C, 0, 0, 0);
      C = __builtin_amdgcn_mfma_f32_16x16x32_bf16(Ah[t], BL, C, 0, 0, 0);
      if (t < 7) {
        mx = fmaxf(mx, fmaxf(fmaxf(C[0], C[1]), fmaxf(C[2], C[3])));
      } else if (lane < 32) {   // tile 7: f 112..119 valid, 120..127 pad
        mx = fmaxf(mx, fmaxf(fmaxf(C[0], C[1]), fmaxf(C[2], C[3])));
      }
    }
    mx = fmaxf(mx, __shfl_xor(mx, 16));
    mx = fmaxf(mx, __shfl_xor(mx, 32));
    if (lane < 16) {
      const float e = expf(2.f * mx - msq - psq);   // exp(-min_dist) <= ~1
      exprow[(j << 4) + r] = e;
      psum += e;
    }
  }

  // block partial sum
  #pragma unroll
  for (int off = 32; off >= 1; off >>= 1) psum += __shfl_xor(psum, off);
  if (lane == 0) sred[w] = psum;
  __syncthreads();

  // pairwise self-validating sum exchange (value, ~bits) via ws
  if (tid == 0) {
    float mysum = 0.f;
    #pragma unroll
    for (int i = 0; i < 16; ++i) mysum += sred[i];
    const unsigned sb = __builtin_bit_cast(unsigned, mysum);
    __hip_atomic_store(&wsp[2 * bid], sb, __ATOMIC_RELAXED, __HIP_MEMORY_SCOPE_AGENT);
    __hip_atomic_store(&wsp[2 * bid + 1], ~sb, __ATOMIC_RELEASE, __HIP_MEMORY_SCOPE_AGENT);
    const int pb = bid ^ 1;
    unsigned pw1, pw2;
    do {
      pw2 = __hip_atomic_load(&wsp[2 * pb + 1], __ATOMIC_ACQUIRE, __HIP_MEMORY_SCOPE_AGENT);
      pw1 = __hip_atomic_load(&wsp[2 * pb], __ATOMIC_RELAXED, __HIP_MEMORY_SCOPE_AGENT);
    } while (pw1 != ~pw2);
    sred[16] = mysum + __builtin_bit_cast(float, pw1);
  }
  __syncthreads();

  // normalize + coalesced write of this half's px range
  const float inv = 1.0f / sred[16];
  const int n = NT << 4;   // 1792 or 1808
  #pragma unroll
  for (int i = 0; i < 2; ++i) {
    const int idx = tid + (i << 10);
    if (idx < n) out[rowbase + px0 + idx] = exprow[idx] * inv;
  }
}

extern "C" void kernel_launch(void* const* d_in, const int* in_sizes, int n_in,
                              void* d_out, int out_size, void* d_ws, size_t ws_size,
                              hipStream_t stream) {
  const float* x = (const float*)d_in[0];
  const float* kern = (const float*)d_in[1];
  float* out = (float*)d_out;
  unsigned* wsp = (unsigned*)d_ws;
  hipLaunchKernelGGL(fused, dim3(NBLK), dim3(1024), 0, stream, x, kern, wsp, out);
}

// Round 13
// 22.990 us; speedup vs baseline: 1.5380x; 1.1156x over previous
//
#include <hip/hip_runtime.h>
#include <math.h>

#define LC 8
#define FAC 120
#define KS 5
#define KK 25
#define IWID 64
#define NH 60
#define SS 3600
#define HALF0PX 1792     // half0: tiles 0..111 (px 0..1791); half1: 113 tiles (px 1792..3599)
#define NBLK 256         // 128 rows (plane,l) x 2 halves

using f16x8 = __attribute__((ext_vector_type(8))) _Float16;
using f32x4 = __attribute__((ext_vector_type(4))) float;

// One block = half of one output row (plane,l). Whole x-plane in LDS; M-slice
// in fp16 (single MFMA term: error 2^-11, ~6x under threshold; psq/msq exact
// f32). Barrier-free main loop; pairwise self-validating sum exchange via ws.
__global__ __launch_bounds__(1024) void fused(const float* __restrict__ x,
                                              const float* __restrict__ kern,
                                              unsigned* __restrict__ wsp,
                                              float* __restrict__ out) {
  __shared__ float plane_s[IWID * IWID];       // 16 KB
  __shared__ _Float16 Mf[128][32];             // 8 KB; f 120..127 zero, q 25..31 zero
  __shared__ float exprow[1808];               // this half's exp values
  __shared__ float sred[17];                   // [0..15] wave sums, [16] msq

  const int tid = threadIdx.x;
  const int bid = blockIdx.x;
  const int row = bid >> 1;                    // plane*8 + l
  const int half = bid & 1;
  const int plane = row >> 3;
  const int l = row & 7;
  const int w = tid >> 6;
  const int lane = tid & 63;
  const int h = lane >> 4;
  const int r = lane & 15;
  const int rowbase = ((plane >> 1) * 16 + (plane & 1) * 8 + l) * SS;
  const int px0 = half * HALF0PX;
  const int NT = 112 + half;                   // tiles this half

  // x-plane -> LDS (1024 x float4, coalesced)
  ((f32x4*)plane_s)[tid] = ((const f32x4*)(x + plane * (IWID * IWID)))[tid];
  if (bid == 0 && tid < LC * KK) out[460800 + tid] = kern[tid];   // tuple tail

  // M-slice build, parallel: 8 threads per f-row, 4 q-slots each
  {
    const int f = tid >> 3;
    const int sub = tid & 7;
    if (f < FAC) {
      int avail[KS] = {0, 1, 2, 3, 4};
      int perm[KS];
      int rem = f;
      const int divs[4] = {24, 6, 2, 1};
      #pragma unroll
      for (int i = 0; i < 4; ++i) {
        const int d = rem / divs[i];
        rem -= d * divs[i];
        perm[i] = avail[d];
        for (int j = d; j < 4 - i; ++j) avail[j] = avail[j + 1];
      }
      perm[4] = avail[0];
      const float* Kl = kern + l * KK;
      #pragma unroll
      for (int i = 0; i < 4; ++i) {
        const int q = (sub << 2) + i;
        _Float16 hv = (_Float16)0.f;
        if (q < KK) {
          const int a = (q * 13) >> 6;         // q/5 for q<32
          const int d = q - a * KS;
          hv = (_Float16)Kl[perm[a] * KS + perm[d]];   // RNE cvt
        }
        Mf[f][q] = hv;
      }
    } else {
      #pragma unroll
      for (int i = 0; i < 4; ++i) Mf[f][(sub << 2) + i] = (_Float16)0.f;
    }
    if (tid == 0) {   // exact f32 msq (overlaps other threads' build)
      const float* Kl = kern + l * KK;
      float s = 0.f;
      #pragma unroll
      for (int q = 0; q < KK; ++q) s = fmaf(Kl[q], Kl[q], s);
      sred[16] = s;
    }
  }
  __syncthreads();   // plane + M + msq ready

  // A fragments once per wave (8 x ds_read_b128)
  const _Float16* ap = &Mf[0][0] + r * 32 + h * 8;
  f16x8 Af[8];
  #pragma unroll
  for (int t = 0; t < 8; ++t) Af[t] = *(const f16x8*)(ap + t * 512);
  const float msq = sred[16];
  const f32x4 Z = {0.f, 0.f, 0.f, 0.f};

  // per-lane gather offsets + multiplicative mask for q = 8h..8h+7
  int offs[8];
  float mk[8];
  #pragma unroll
  for (int e = 0; e < 8; ++e) {
    const int q = (h << 3) + e;
    const bool valid = (q < KK);
    offs[e] = valid ? ((q / KS) * IWID + (q % KS)) : 0;
    mk[e] = valid ? 1.f : 0.f;
  }

  float psum = 0.f;
  // main loop: NT 16-px tiles striped over 16 waves, barrier-free
  #pragma unroll 1
  for (int j = w; j < NT; j += 16) {
    const int px = px0 + (j << 4) + r;
    const int ih = px / NH;
    const int iw = px - ih * NH;
    const int base = ih * IWID + iw;
    f16x8 B;
    float psq = 0.f;
    #pragma unroll
    for (int e = 0; e < 8; ++e) {
      const float v = plane_s[base + offs[e]] * mk[e];
      psq = fmaf(v, v, psq);        // exact f32 ||patch||^2 (not fp16-rounded)
      B[e] = (_Float16)v;           // RNE cvt, only the cross term is rounded
    }
    psq += __shfl_xor(psq, 16);
    psq += __shfl_xor(psq, 32);
    float mx = -INFINITY;
    #pragma unroll
    for (int t = 0; t < 8; ++t) {
      const f32x4 C = __builtin_amdgcn_mfma_f32_16x16x32_f16(Af[t], B, Z, 0, 0, 0);
      if (t < 7) {
        mx = fmaxf(fmaxf(fmaxf(C[0], C[1]), fmaxf(C[2], C[3])), mx);
      } else if (lane < 32) {   // tile 7: f 112..119 valid, 120..127 pad
        mx = fmaxf(fmaxf(fmaxf(C[0], C[1]), fmaxf(C[2], C[3])), mx);
      }
    }
    mx = fmaxf(mx, __shfl_xor(mx, 16));
    mx = fmaxf(mx, __shfl_xor(mx, 32));
    if (lane < 16) {
      const float e = expf(2.f * mx - msq - psq);   // exp(-min_dist) <= ~1
      exprow[(j << 4) + r] = e;
      psum += e;
    }
  }

  // block partial sum
  #pragma unroll
  for (int off = 32; off >= 1; off >>= 1) psum += __shfl_xor(psum, off);
  if (lane == 0) sred[w] = psum;
  __syncthreads();

  // pairwise self-validating sum exchange (value, ~bits) via ws
  if (tid == 0) {
    float mysum = 0.f;
    #pragma unroll
    for (int i = 0; i < 16; ++i) mysum += sred[i];
    const unsigned sb = __builtin_bit_cast(unsigned, mysum);
    __hip_atomic_store(&wsp[2 * bid], sb, __ATOMIC_RELAXED, __HIP_MEMORY_SCOPE_AGENT);
    __hip_atomic_store(&wsp[2 * bid + 1], ~sb, __ATOMIC_RELEASE, __HIP_MEMORY_SCOPE_AGENT);
    const int pb = bid ^ 1;
    unsigned pw1, pw2;
    do {
      pw2 = __hip_atomic_load(&wsp[2 * pb + 1], __ATOMIC_ACQUIRE, __HIP_MEMORY_SCOPE_AGENT);
      pw1 = __hip_atomic_load(&wsp[2 * pb], __ATOMIC_RELAXED, __HIP_MEMORY_SCOPE_AGENT);
    } while (pw1 != ~pw2);
    sred[16] = mysum + __builtin_bit_cast(float, pw1);
  }
  __syncthreads();

  // normalize + coalesced write of this half's px range
  const float inv = 1.0f / sred[16];
  const int n = NT << 4;   // 1792 or 1808
  #pragma unroll
  for (int i = 0; i < 2; ++i) {
    const int idx = tid + (i << 10);
    if (idx < n) out[rowbase + px0 + idx] = exprow[idx] * inv;
  }
}

extern "C" void kernel_launch(void* const* d_in, const int* in_sizes, int n_in,
                              void* d_out, int out_size, void* d_ws, size_t ws_size,
                              hipStream_t stream) {
  const float* x = (const float*)d_in[0];
  const float* kern = (const float*)d_in[1];
  float* out = (float*)d_out;
  unsigned* wsp = (unsigned*)d_ws;
  hipLaunchKernelGGL(fused, dim3(NBLK), dim3(1024), 0, stream, x, kern, wsp, out);
}